// Round 7
// baseline (112.361 us; speedup 1.0000x reference)
//
#include <hip/hip_runtime.h>

#define NN 8192
#define DD 128
#define MAXCLS 64   // max members per class; Binom(8192,1/1024) mean 8 -> P(>64) negligible
#define NCHUNK 8    // j-chunks in the GEMM phase
#define NBLK 256    // fused grid: 1 block/CU x 256 CU, co-resident by construction
#define TPB  512    // 8 waves/block
#define LOG2E 1.4426950408889634f
#define E1    2.718281828459045f   // e^margin, margin = 1

typedef __attribute__((ext_vector_type(8))) short bf16x8;
typedef __attribute__((ext_vector_type(4))) float f32x4;

#if __has_builtin(__builtin_amdgcn_exp2f)
#define EXP2F(x) __builtin_amdgcn_exp2f(x)
#else
#define EXP2F(x) exp2f(x)
#endif

// async global->LDS 16B: per-lane global address, LDS dest = wave-uniform base + lane*16
__device__ __forceinline__ void load16_lds(const unsigned short* g, unsigned short* l) {
    __builtin_amdgcn_global_load_lds(
        (const __attribute__((address_space(1))) unsigned int*)g,
        (__attribute__((address_space(3))) unsigned int*)l,
        16, 0, 0);
}

__device__ __forceinline__ unsigned short f2bf(float x) {
    unsigned u = __float_as_uint(x);
    u = (u + 0x7FFFu + ((u >> 16) & 1u)) >> 16;
    return (unsigned short)u;
}

// sc1 write-through stores: relaxed AGENT-scope atomic stores write at the coherent
// point (LLC) and never allocate in L1/L2. ALL cross-phase data uses these ->
// no L2 ever holds a dirty OR stale copy of cross-phase data -> barriers need NO
// cache maintenance at all.
__device__ __forceinline__ void st_agent(float* p, float v) {
    __hip_atomic_store(p, v, __ATOMIC_RELAXED, __HIP_MEMORY_SCOPE_AGENT);
}
__device__ __forceinline__ void st_agent(int* p, int v) {
    __hip_atomic_store(p, v, __ATOMIC_RELAXED, __HIP_MEMORY_SCOPE_AGENT);
}
__device__ __forceinline__ void st_agent(unsigned int* p, unsigned int v) {
    __hip_atomic_store(p, v, __ATOMIC_RELAXED, __HIP_MEMORY_SCOPE_AGENT);
}
__device__ __forceinline__ void st_agent(unsigned long long* p, unsigned long long v) {
    __hip_atomic_store(p, v, __ATOMIC_RELAXED, __HIP_MEMORY_SCOPE_AGENT);
}
__device__ __forceinline__ unsigned int ld_agent(const unsigned int* p) {
    return __hip_atomic_load(p, __ATOMIC_RELAXED, __HIP_MEMORY_SCOPE_AGENT);
}

// HW_REG_XCC_ID (id=20) [measured: learn_hip m09]. Correctness only needs
// per-block consistency (grouping key), not accuracy.
__device__ __forceinline__ int xcd_id() {
    return (int)(__builtin_amdgcn_s_getreg(20 | (0 << 6) | (31 << 11)) & 7u);
}

// ---------------- device-scope grid barrier, zero cache maintenance ----------------
// (R6 structure, absmax-0 verified): 128B-separated counters, one relay per XCD
// claimed once, relaxed arrivals, no release/acquire/inv (all cross-phase data sc1 +
// first-touch-after-sync). Spins carry ~7ms timeout escapes: failure => wrong
// answer (absmax flags it), never a hung container.
__device__ __forceinline__ void grid_sync(int* subcnt, int* root, unsigned int* gen,
                                          unsigned int* doneg, int relay, int myxcd,
                                          int sub) {
    __syncthreads();   // every wave drains vmcnt -> all sc1 stores complete at LLC
    if (threadIdx.x == 0) {
        unsigned int g = ld_agent(gen);   // gen can't advance past g before we arrive
        int v = __hip_atomic_fetch_add(&subcnt[sub * 32], 1,
                                       __ATOMIC_RELAXED, __HIP_MEMORY_SCOPE_AGENT);
        if (v == (NBLK / 8) - 1) {           // last arrival on this sub-counter
            __hip_atomic_store(&subcnt[sub * 32], 0, __ATOMIC_RELAXED, __HIP_MEMORY_SCOPE_AGENT);
            int r = __hip_atomic_fetch_add(root, 1, __ATOMIC_RELAXED, __HIP_MEMORY_SCOPE_AGENT);
            if (r == 7) {                    // whole grid arrived
                __hip_atomic_store(root, 0, __ATOMIC_RELAXED, __HIP_MEMORY_SCOPE_AGENT);
                st_agent(gen, g + 1u);
            }
        }
        if (relay) {
            long long t0 = clock64();
            while (ld_agent(gen) == g) {
                __builtin_amdgcn_s_sleep(1);
                if (clock64() - t0 > (1LL << 24)) break;   // ~7ms escape hatch
            }
            st_agent(&doneg[myxcd * 32], g + 1u);          // repost on per-XCD line
        } else {
            long long t1 = clock64();
            while ((int)(ld_agent(&doneg[myxcd * 32]) - (g + 1u)) < 0) {
                __builtin_amdgcn_s_sleep(1);
                if (clock64() - t1 > (1LL << 24)) break;
            }
        }
    }
    __syncthreads();
}

// ---------------- fused kernel: convert+bucket | gemm+vsum | pairs | finalize ----------------
// R7: 256-row GEMM blocks (grid 256x512thr) -> staged-B traffic HALVES (128->64MB).
// Per-wave register structure identical to R6 (afr[4][4], acc[4][4]); wi spans 4
// row-halves, wj 2 col-halves. A staged through Bs[0] in two 128-row rounds.
__global__ __launch_bounds__(TPB, 2) void ml_fused_kernel(
    const float* __restrict__ a, const float* __restrict__ b,
    const int* __restrict__ labels,
    unsigned short* __restrict__ abf, unsigned short* __restrict__ bbf,
    int* __restrict__ cnt, int* __restrict__ list,
    float* __restrict__ Vp,
    float* __restrict__ classLoss, int* __restrict__ classCnt,
    float* __restrict__ out,
    int* subcnt, int* root, unsigned int* gen,
    int* claim, unsigned int* doneg)
{
    // LDS: [0,65536) = Bs[2][128*DD] (GEMM) / [0,73728) = 4x18432 phase-C quarters
    //      [73728,74240) = red[4][64] (GEMM cross-wave combine)
    __shared__ char SM[74240];
    unsigned short (*Bs)[128 * DD] = (unsigned short (*)[128 * DD])SM;
    float* red = (float*)(SM + 73728);

    const int tid = threadIdx.x;
    const int bid = blockIdx.x;
    const int sub = bid & 7;

    // one-time relay claim (first block per XCD value wins); only thread 0's copy matters
    int relay = 0, myxcd = 0;
    if (tid == 0) {
        myxcd = xcd_id();
        relay = (__hip_atomic_fetch_add(&claim[myxcd * 32], 1,
                                        __ATOMIC_RELAXED, __HIP_MEMORY_SCOPE_AGENT) == 0);
    }

    // ================= phase A: fp32->bf16 convert + class bucketing =================
#pragma unroll
    for (int it = 0; it < 4; it++) {
        int t = it * (NBLK * TPB) + bid * TPB + tid;   // 0 .. 524287
        const float* src = a;
        unsigned short* dst = abf;
        int idx = t;
        float scale = LOG2E;                           // A rows carry the log2e factor
        if (t >= 262144) { src = b; dst = bbf; idx = t - 262144; scale = 1.0f; }
        float4 v = ((const float4*)src)[idx];
        ushort4 o;
        o.x = f2bf(v.x * scale); o.y = f2bf(v.y * scale);
        o.z = f2bf(v.z * scale); o.w = f2bf(v.w * scale);
        union { ushort4 v4; unsigned long long u; } cvt;
        cvt.v4 = o;
        st_agent(((unsigned long long*)dst) + idx, cvt.u);   // sc1: straight to LLC
        if (t < NN) {
            int c = labels[t];
            int p = atomicAdd(&cnt[c], 1);               // device-scope RMW at LLC
            if (p < MAXCLS) st_agent(&list[c * MAXCLS + p], t);
        }
    }

    grid_sync(subcnt, root, gen, doneg, relay, myxcd, sub);

    // ================= phase B: flash-style GEMM + unmasked exp2 row-sum =================
    {
        const int lane = tid & 63;
        const int wv   = tid >> 6;            // 0..7
        const int row0 = (bid >> 3) * 256;    // 32 row-blocks of 256 rows
        const int j0   = (bid & 7) * 1024;    // 8 j-chunks

        const int lr = lane >> 4;      // staging: row-within-4
        const int sp = lane & 15;      // staging: slot
        const int m  = lane & 15;      // mfma row/col lane
        const int q  = lane >> 4;
        const int xr = m & 7;          // read-side swizzle key

        // per-wave stage of one 128-row tile: wave wv covers rows wv*16 .. wv*16+15
#define STAGE128(SRCBASE, BUF)                                                         \
        _Pragma("unroll")                                                              \
        for (int i = 0; i < 4; i++) {                                                  \
            int rb = wv * 16 + i * 4;                                                  \
            int r  = rb + lr;                                                          \
            int cc = sp ^ (r & 7);                                                     \
            load16_lds(&(SRCBASE)[(size_t)r * DD + cc * 8], &Bs[BUF][rb * DD]);        \
        }

        // ---- prologue: A rows 0..127 -> Bs[0], B tile0 -> Bs[1] ----
        STAGE128(&abf[(size_t)row0 * DD], 0);
        STAGE128(&bbf[(size_t)j0 * DD], 1);
        __syncthreads();               // drains staging: A-r0 + tile0 ready

        const int wi = (wv >> 1) * 64;   // row-quarter of the 256-row block
        const int wj = (wv & 1) * 64;    // col-half of the 128-col tile

        // ---- A fragments -> registers (two rounds through Bs[0]) ----
        bf16x8 afr[4][4];
        if (wv < 4) {                    // rows 0..127 resident now
#pragma unroll
            for (int ti = 0; ti < 4; ti++)
#pragma unroll
                for (int ks = 0; ks < 4; ks++) {
                    int r   = wi + ti * 16 + m;
                    int pos = (ks * 4 + q) ^ xr;
                    afr[ti][ks] = *(const bf16x8*)(&Bs[0][r * DD + pos * 8]);
                }
        }
        asm volatile("s_waitcnt lgkmcnt(0)" ::: "memory");
        __syncthreads();

        STAGE128(&abf[(size_t)(row0 + 128) * DD], 0);   // A rows 128..255 -> Bs[0]
        __syncthreads();
        if (wv >= 4) {
#pragma unroll
            for (int ti = 0; ti < 4; ti++)
#pragma unroll
                for (int ks = 0; ks < 4; ks++) {
                    int r   = (wi - 128) + ti * 16 + m;
                    int pos = (ks * 4 + q) ^ xr;
                    afr[ti][ks] = *(const bf16x8*)(&Bs[0][r * DD + pos * 8]);
                }
        }
        asm volatile("s_waitcnt lgkmcnt(0)" ::: "memory");
        __syncthreads();

        // issue B tile1 -> Bs[0] (4 outstanding entering the loop)
        STAGE128(&bbf[(size_t)(j0 + 128) * DD], 0);

        float rs[4][4];
#pragma unroll
        for (int ti = 0; ti < 4; ti++)
#pragma unroll
            for (int rg = 0; rg < 4; rg++) rs[ti][rg] = 0.f;

        const f32x4 zero = {0.f, 0.f, 0.f, 0.f};
        f32x4 acc[4][4];

#define COMPUTE_TILE(BUF)                                                              \
        {                                                                              \
            __builtin_amdgcn_s_setprio(1);                                             \
            _Pragma("unroll")                                                          \
            for (int ks = 0; ks < 4; ks++) {                                           \
                bf16x8 bfr[4];                                                         \
                _Pragma("unroll")                                                      \
                for (int tj = 0; tj < 4; tj++) {                                       \
                    int r   = wj + tj * 16 + m;                                        \
                    int pos = (ks * 4 + q) ^ xr;                                       \
                    bfr[tj] = *(const bf16x8*)(&Bs[BUF][r * DD + pos * 8]);            \
                }                                                                      \
                _Pragma("unroll")                                                      \
                for (int ti = 0; ti < 4; ti++)                                         \
                    _Pragma("unroll")                                                  \
                    for (int tj = 0; tj < 4; tj++)                                     \
                        acc[ti][tj] = __builtin_amdgcn_mfma_f32_16x16x32_bf16(         \
                            afr[ti][ks], bfr[tj], (ks == 0) ? zero : acc[ti][tj],      \
                            0, 0, 0);                                                  \
            }                                                                          \
            __builtin_amdgcn_s_setprio(0);                                             \
        }

#define EPILOGUE()                                                                     \
        _Pragma("unroll")                                                              \
        for (int ti = 0; ti < 4; ti++)                                                 \
            _Pragma("unroll")                                                          \
            for (int tj = 0; tj < 4; tj++) {                                           \
                f32x4 c = acc[ti][tj];                                                 \
                rs[ti][0] += EXP2F(c[0]);                                              \
                rs[ti][1] += EXP2F(c[1]);                                              \
                rs[ti][2] += EXP2F(c[2]);                                              \
                rs[ti][3] += EXP2F(c[3]);                                              \
            }

        // ---- steady state: tiles 0..5 (tile jt lives in Bs[(jt+1)&1]) ----
#pragma unroll 2
        for (int jt = 0; jt < 6; jt++) {
            const int cb = (jt + 1) & 1;
            COMPUTE_TILE(cb);
            asm volatile("s_waitcnt lgkmcnt(0)" ::: "memory"); // bfr reads done
            __builtin_amdgcn_s_barrier();                      // all waves done with Bs[cb]
            STAGE128(&bbf[(size_t)(j0 + (jt + 2) * 128) * DD], cb);  // issue jt+2
            EPILOGUE();                                        // register-only; covers flight
            // wait own tile jt+1 loads (4 newest = jt+2's stay IN FLIGHT across barrier)
            asm volatile("s_waitcnt vmcnt(4)" ::: "memory");
            __builtin_amdgcn_s_barrier();
        }
        {   // jt = 6: compute Bs[1]; nothing left to stage
            COMPUTE_TILE(1);
            EPILOGUE();
            asm volatile("s_waitcnt vmcnt(0)" ::: "memory");   // tile7 landed
            __builtin_amdgcn_s_barrier();
        }
        {   // jt = 7: last tile from Bs[0]
            COMPUTE_TILE(0);
            EPILOGUE();
        }

#undef COMPUTE_TILE
#undef STAGE128
#undef EPILOGUE

        // ---- reduce over the 16 col-lanes ----
#pragma unroll
        for (int ti = 0; ti < 4; ti++)
#pragma unroll
            for (int rg = 0; rg < 4; rg++) {
                float v = rs[ti][rg];
                v += __shfl_xor(v, 1);
                v += __shfl_xor(v, 2);
                v += __shfl_xor(v, 4);
                v += __shfl_xor(v, 8);
                rs[ti][rg] = v;
            }

        // ---- cross-wave combine (odd waves deposit; even waves add + store) ----
        if ((wv & 1) == 1 && m == 0) {
#pragma unroll
            for (int ti = 0; ti < 4; ti++)
#pragma unroll
                for (int rg = 0; rg < 4; rg++)
                    red[(wv >> 1) * 64 + ti * 16 + q * 4 + rg] = rs[ti][rg];
        }
        __syncthreads();
        if ((wv & 1) == 0 && m == 0) {
#pragma unroll
            for (int ti = 0; ti < 4; ti++)
#pragma unroll
                for (int rg = 0; rg < 4; rg++) {
                    int rloc = ti * 16 + q * 4 + rg;
                    st_agent(&Vp[(size_t)(bid & 7) * NN + row0 + wi + rloc],
                             rs[ti][rg] + red[(wv >> 1) * 64 + rloc]);
                }
        }
    }

    grid_sync(subcnt, root, gen, doneg, relay, myxcd, sub);

    // ================= phase C: per-class pairs — 4 classes CONCURRENT (128-thr quarters) =======
    {
        char* sm = (char*)SM;
        const int h  = tid >> 7;          // quarter 0..3
        const int ht = tid & 127;         // tid within quarter
        int*   mem    = (int*)  (sm + h * 18432);           // 256 B
        float* sumExp = (float*)(sm + h * 18432 + 256);     // 256 B
        float* Vadj   = (float*)(sm + h * 18432 + 512);     // 256 B
        float* Sc     = (float*)(sm + h * 18432 + 1024);    // 16 KB
        float* ps     = (float*)(sm + h * 18432 + 17408);   // 8 B (2 waves/quarter)
        int*   cs     = (int*)  (sm + h * 18432 + 17424);   // 8 B

        const int c = bid * 4 + h;        // classes 0..1023
        int mc = cnt[c];                  // first in-kernel read -> L2 miss -> fresh LLC
        if (mc > MAXCLS) mc = MAXCLS;

        float vsum = 0.f;
        if (ht < mc) {
            int r = list[c * MAXCLS + ht];
            mem[ht] = r;
#pragma unroll
            for (int jc = 0; jc < NCHUNK; jc++) vsum += Vp[(size_t)jc * NN + r];
        }
        if (ht < MAXCLS) sumExp[ht] = 0.f;
        __syncthreads();   // block-wide; all quarters hit it exactly once

        // phase 1: mc^2 dots (8 groups of 16 lanes per quarter), cache S, exp sums
        const int g = ht >> 4;
        const int l = ht & 15;
        const int tot1 = mc * mc;
        for (int pp = g; pp < tot1; pp += 8) {
            int i = pp / mc;
            int j = pp - i * mc;
            int ri = mem[i], rj = mem[j];
            const float4* ar = (const float4*)(a + (size_t)ri * DD) + l * 2;
            const float4* br = (const float4*)(b + (size_t)rj * DD) + l * 2;
            float4 a0 = ar[0], a1 = ar[1];
            float4 b0 = br[0], b1 = br[1];
            float s = 0.f;
            s = fmaf(a0.x, b0.x, s); s = fmaf(a0.y, b0.y, s);
            s = fmaf(a0.z, b0.z, s); s = fmaf(a0.w, b0.w, s);
            s = fmaf(a1.x, b1.x, s); s = fmaf(a1.y, b1.y, s);
            s = fmaf(a1.z, b1.z, s); s = fmaf(a1.w, b1.w, s);
            s += __shfl_xor(s, 1);
            s += __shfl_xor(s, 2);
            s += __shfl_xor(s, 4);
            s += __shfl_xor(s, 8);
            if (l == 0) {
                Sc[i * MAXCLS + j] = s;
                atomicAdd(&sumExp[i], __expf(s));   // LDS atomic
            }
        }
        __syncthreads();

        if (ht < mc) Vadj[ht] = E1 * (vsum - sumExp[ht]);
        __syncthreads();

        // phase 2: one thread per ordered pair (i != j), 128 threads per quarter
        float partial = 0.f;
        int   count   = 0;
        for (int pp = ht; pp < tot1; pp += 128) {
            int i = pp / mc;
            int j = pp - i * mc;
            if (i != j) {
                float hg = fmaxf(logf(Vadj[i] + Vadj[j]) - Sc[i * MAXCLS + j], 0.f);
                partial += hg * hg;
                count++;
            }
        }
        for (int off = 32; off > 0; off >>= 1) {
            partial += __shfl_down(partial, off);
            count   += __shfl_down(count, off);
        }
        if ((ht & 63) == 0) { ps[ht >> 6] = partial; cs[ht >> 6] = count; }
        __syncthreads();
        if (ht == 0) {
            st_agent(&classLoss[c], ps[0] + ps[1]);
            st_agent(&classCnt[c],  cs[0] + cs[1]);
        }
    }

    // ========== finalize: spread arrival tree; LAST block reduces, others exit ==========
    __syncthreads();   // all waves drain vmcnt -> this block's sc1 stores are at LLC
    __shared__ int amLast;
    if (tid == 0) {
        int last = 0;
        int v = __hip_atomic_fetch_add(&subcnt[sub * 32], 1,
                                       __ATOMIC_RELAXED, __HIP_MEMORY_SCOPE_AGENT);
        if (v == (NBLK / 8) - 1) {
            __hip_atomic_store(&subcnt[sub * 32], 0, __ATOMIC_RELAXED, __HIP_MEMORY_SCOPE_AGENT);
            int r = __hip_atomic_fetch_add(root, 1, __ATOMIC_RELAXED, __HIP_MEMORY_SCOPE_AGENT);
            if (r == 7) { __hip_atomic_store(root, 0, __ATOMIC_RELAXED, __HIP_MEMORY_SCOPE_AGENT); last = 1; }
        }
        amLast = last;
    }
    __syncthreads();
    if (amLast) {
        __shared__ double dred[8];
        __shared__ long long cred[8];
        const int lane = tid & 63, wvv = tid >> 6;
        double dls = 0.0;
        long long dct = 0;
        for (int k = tid; k < 1024; k += TPB) {
            dls += (double)__hip_atomic_load(&classLoss[k], __ATOMIC_RELAXED, __HIP_MEMORY_SCOPE_AGENT);
            dct += (long long)__hip_atomic_load(&classCnt[k], __ATOMIC_RELAXED, __HIP_MEMORY_SCOPE_AGENT);
        }
        for (int off = 32; off > 0; off >>= 1) {
            dls += __shfl_down(dls, off);
            dct += __shfl_down(dct, off);
        }
        if (lane == 0) { dred[wvv] = dls; cred[wvv] = dct; }
        __syncthreads();
        if (tid == 0) {
            double ls = 0.0;
            long long np = 0;
#pragma unroll
            for (int w = 0; w < 8; w++) { ls += dred[w]; np += cred[w]; }
            out[0] = (float)(ls / (2.0 * (double)np));
        }
    }
}

// ---------------- launch ----------------
extern "C" void kernel_launch(void* const* d_in, const int* in_sizes, int n_in,
                              void* d_out, int out_size, void* d_ws, size_t ws_size,
                              hipStream_t stream)
{
    const float* a      = (const float*)d_in[0];
    const float* b      = (const float*)d_in[1];
    const int*   labels = (const int*)d_in[2];
    float* out = (float*)d_out;

    char* ws = (char*)d_ws;
    // ws layout:
    //   [0, 2MB)   a_bf16 (scaled by log2e)    [2MB, 4MB)  b_bf16
    //   base2 = 4MB (first 8KB memset to 0); every barrier word on its OWN 128B line:
    //     +0     cnt[1024]              4096 B
    //     +4096  subcnt[8]  @128B stride  1 KB
    //     +5120  root
    //     +5248  gen
    //     +5376  claim[8]   @128B stride  1 KB
    //     +6400  doneg[8]   @128B stride  1 KB
    //     +8192  classLoss[1024] f32    4096 B
    //     +12288 classCnt[1024] int     4096 B
    //     +16384 list[1024*64]          256 KB
    //     +278528 Vp[8*8192] f32        256 KB
    unsigned short* abf = (unsigned short*)ws;
    unsigned short* bbf = (unsigned short*)(ws + 2097152);
    char*     base2     = ws + 4194304;
    int*      cnt       = (int*)(base2);
    int*      subcnt    = (int*)(base2 + 4096);
    int*      root      = (int*)(base2 + 5120);
    unsigned int* gen   = (unsigned int*)(base2 + 5248);
    int*      claim     = (int*)(base2 + 5376);
    unsigned int* doneg = (unsigned int*)(base2 + 6400);
    float*    classLoss = (float*)(base2 + 8192);
    int*      classCnt  = (int*)(base2 + 12288);
    int*      list      = (int*)(base2 + 16384);
    float*    Vp        = (float*)(base2 + 278528);

    (void)hipMemsetAsync(cnt, 0, 8192, stream);   // zeros cnt + all barrier state

    ml_fused_kernel<<<NBLK, TPB, 0, stream>>>(
        a, b, labels, abf, bbf, cnt, list, Vp, classLoss, classCnt, out,
        subcnt, root, gen, claim, doneg);
}

// Round 8
// 107.871 us; speedup vs baseline: 1.0416x; 1.0416x over previous
//
#include <hip/hip_runtime.h>

#define NN 8192
#define DD 128
#define MAXCLS 64   // max members per class; Binom(8192,1/1024) mean 8 -> P(>64) negligible
#define NCHUNK 8    // j-chunks in the GEMM phase
#define NBLK 256    // fused grid: 1 block/CU x 256 CU, co-resident by construction
#define TPB  512    // 8 waves/block
#define LOG2E 1.4426950408889634f
#define E1    2.718281828459045f   // e^margin, margin = 1

typedef __attribute__((ext_vector_type(8))) short bf16x8;
typedef __attribute__((ext_vector_type(4))) float f32x4;

#if __has_builtin(__builtin_amdgcn_exp2f)
#define EXP2F(x) __builtin_amdgcn_exp2f(x)
#else
#define EXP2F(x) exp2f(x)
#endif

// async global->LDS 16B: per-lane global address, LDS dest = wave-uniform base + lane*16
__device__ __forceinline__ void load16_lds(const unsigned short* g, unsigned short* l) {
    __builtin_amdgcn_global_load_lds(
        (const __attribute__((address_space(1))) unsigned int*)g,
        (__attribute__((address_space(3))) unsigned int*)l,
        16, 0, 0);
}

__device__ __forceinline__ unsigned short f2bf(float x) {
    unsigned u = __float_as_uint(x);
    u = (u + 0x7FFFu + ((u >> 16) & 1u)) >> 16;
    return (unsigned short)u;
}

// sc1 write-through stores: relaxed AGENT-scope atomic stores write at the coherent
// point (LLC) and never allocate in L1/L2. ALL cross-phase data uses these ->
// no L2 ever holds a dirty OR stale copy of cross-phase data -> barriers need NO
// cache maintenance at all.
__device__ __forceinline__ void st_agent(float* p, float v) {
    __hip_atomic_store(p, v, __ATOMIC_RELAXED, __HIP_MEMORY_SCOPE_AGENT);
}
__device__ __forceinline__ void st_agent(int* p, int v) {
    __hip_atomic_store(p, v, __ATOMIC_RELAXED, __HIP_MEMORY_SCOPE_AGENT);
}
__device__ __forceinline__ void st_agent(unsigned int* p, unsigned int v) {
    __hip_atomic_store(p, v, __ATOMIC_RELAXED, __HIP_MEMORY_SCOPE_AGENT);
}
__device__ __forceinline__ void st_agent(unsigned long long* p, unsigned long long v) {
    __hip_atomic_store(p, v, __ATOMIC_RELAXED, __HIP_MEMORY_SCOPE_AGENT);
}
__device__ __forceinline__ unsigned int ld_agent(const unsigned int* p) {
    return __hip_atomic_load(p, __ATOMIC_RELAXED, __HIP_MEMORY_SCOPE_AGENT);
}

// HW_REG_XCC_ID (id=20) [measured: learn_hip m09]. Correctness only needs
// per-block consistency (grouping key), not accuracy.
__device__ __forceinline__ int xcd_id() {
    return (int)(__builtin_amdgcn_s_getreg(20 | (0 << 6) | (31 << 11)) & 7u);
}

// ---------------- device-scope grid barrier, zero cache maintenance ----------------
// (R6 structure, absmax-0 verified): 128B-separated counters, one relay per XCD
// claimed once, relaxed arrivals, no release/acquire/inv (all cross-phase data sc1 +
// first-touch-after-sync). Spins carry ~7ms timeout escapes: failure => wrong
// answer (absmax flags it), never a hung container.
__device__ __forceinline__ void grid_sync(int* subcnt, int* root, unsigned int* gen,
                                          unsigned int* doneg, int relay, int myxcd,
                                          int sub) {
    __syncthreads();   // every wave drains vmcnt -> all sc1 stores complete at LLC
    if (threadIdx.x == 0) {
        unsigned int g = ld_agent(gen);   // gen can't advance past g before we arrive
        int v = __hip_atomic_fetch_add(&subcnt[sub * 32], 1,
                                       __ATOMIC_RELAXED, __HIP_MEMORY_SCOPE_AGENT);
        if (v == (NBLK / 8) - 1) {           // last arrival on this sub-counter
            __hip_atomic_store(&subcnt[sub * 32], 0, __ATOMIC_RELAXED, __HIP_MEMORY_SCOPE_AGENT);
            int r = __hip_atomic_fetch_add(root, 1, __ATOMIC_RELAXED, __HIP_MEMORY_SCOPE_AGENT);
            if (r == 7) {                    // whole grid arrived
                __hip_atomic_store(root, 0, __ATOMIC_RELAXED, __HIP_MEMORY_SCOPE_AGENT);
                st_agent(gen, g + 1u);
            }
        }
        if (relay) {
            long long t0 = clock64();
            while (ld_agent(gen) == g) {
                __builtin_amdgcn_s_sleep(1);
                if (clock64() - t0 > (1LL << 24)) break;   // ~7ms escape hatch
            }
            st_agent(&doneg[myxcd * 32], g + 1u);          // repost on per-XCD line
        } else {
            long long t1 = clock64();
            while ((int)(ld_agent(&doneg[myxcd * 32]) - (g + 1u)) < 0) {
                __builtin_amdgcn_s_sleep(1);
                if (clock64() - t1 > (1LL << 24)) break;
            }
        }
    }
    __syncthreads();
}

// ---------------- fused kernel: convert+bucket | gemm+vsum | pairs | finalize ----------------
// R8: phase C phase-1 is BLOCK-COOPERATIVE: the block's 4 classes share one pair-
// index space (prefix sums) processed by 32 16-lane groups -> tail drops from
// max(mc^2)/8 serial latency-bound iters (~40, ~17us) to sum(mc^2)/32 (~17, ~6us).
// Per-dot FP order (16 lanes x 8 fmaf + 4 shfl) is byte-identical to prior rounds;
// LDS-atomic sumExp replaced by deterministic ascending-j per-row exp-sum (matches
// the previous pp-ordered accumulation).
__global__ __launch_bounds__(TPB, 2) void ml_fused_kernel(
    const float* __restrict__ a, const float* __restrict__ b,
    const int* __restrict__ labels,
    unsigned short* __restrict__ abf, unsigned short* __restrict__ bbf,
    int* __restrict__ cnt, int* __restrict__ list,
    float* __restrict__ Vp,
    float* __restrict__ classLoss, int* __restrict__ classCnt,
    float* __restrict__ out,
    int* subcnt, int* root, unsigned int* gen,
    int* claim, unsigned int* doneg)
{
    // LDS: [0,65536) = Bs[2][128*DD] (GEMM) / [0,73728) = 4x18432 phase-C quarters
    //      [73728,74240) = red[4][64] (GEMM cross-wave combine) / phase-C mcs+cum
    __shared__ char SM[74240];
    unsigned short (*Bs)[128 * DD] = (unsigned short (*)[128 * DD])SM;
    float* red = (float*)(SM + 73728);

    const int tid = threadIdx.x;
    const int bid = blockIdx.x;
    const int sub = bid & 7;

    // one-time relay claim (first block per XCD value wins); only thread 0's copy matters
    int relay = 0, myxcd = 0;
    if (tid == 0) {
        myxcd = xcd_id();
        relay = (__hip_atomic_fetch_add(&claim[myxcd * 32], 1,
                                        __ATOMIC_RELAXED, __HIP_MEMORY_SCOPE_AGENT) == 0);
    }

    // ================= phase A: fp32->bf16 convert + class bucketing =================
#pragma unroll
    for (int it = 0; it < 4; it++) {
        int t = it * (NBLK * TPB) + bid * TPB + tid;   // 0 .. 524287
        const float* src = a;
        unsigned short* dst = abf;
        int idx = t;
        float scale = LOG2E;                           // A rows carry the log2e factor
        if (t >= 262144) { src = b; dst = bbf; idx = t - 262144; scale = 1.0f; }
        float4 v = ((const float4*)src)[idx];
        ushort4 o;
        o.x = f2bf(v.x * scale); o.y = f2bf(v.y * scale);
        o.z = f2bf(v.z * scale); o.w = f2bf(v.w * scale);
        union { ushort4 v4; unsigned long long u; } cvt;
        cvt.v4 = o;
        st_agent(((unsigned long long*)dst) + idx, cvt.u);   // sc1: straight to LLC
        if (t < NN) {
            int c = labels[t];
            int p = atomicAdd(&cnt[c], 1);               // device-scope RMW at LLC
            if (p < MAXCLS) st_agent(&list[c * MAXCLS + p], t);
        }
    }

    grid_sync(subcnt, root, gen, doneg, relay, myxcd, sub);

    // ================= phase B: flash-style GEMM + unmasked exp2 row-sum =================
    {
        const int lane = tid & 63;
        const int wv   = tid >> 6;            // 0..7
        const int row0 = (bid >> 3) * 256;    // 32 row-blocks of 256 rows
        const int j0   = (bid & 7) * 1024;    // 8 j-chunks

        const int lr = lane >> 4;      // staging: row-within-4
        const int sp = lane & 15;      // staging: slot
        const int m  = lane & 15;      // mfma row/col lane
        const int q  = lane >> 4;
        const int xr = m & 7;          // read-side swizzle key

        // per-wave stage of one 128-row tile: wave wv covers rows wv*16 .. wv*16+15
#define STAGE128(SRCBASE, BUF)                                                         \
        _Pragma("unroll")                                                              \
        for (int i = 0; i < 4; i++) {                                                  \
            int rb = wv * 16 + i * 4;                                                  \
            int r  = rb + lr;                                                          \
            int cc = sp ^ (r & 7);                                                     \
            load16_lds(&(SRCBASE)[(size_t)r * DD + cc * 8], &Bs[BUF][rb * DD]);        \
        }

        // ---- prologue: A rows 0..127 -> Bs[0], B tile0 -> Bs[1] ----
        STAGE128(&abf[(size_t)row0 * DD], 0);
        STAGE128(&bbf[(size_t)j0 * DD], 1);
        __syncthreads();               // drains staging: A-r0 + tile0 ready

        const int wi = (wv >> 1) * 64;   // row-quarter of the 256-row block
        const int wj = (wv & 1) * 64;    // col-half of the 128-col tile

        // ---- A fragments -> registers (two rounds through Bs[0]) ----
        bf16x8 afr[4][4];
        if (wv < 4) {                    // rows 0..127 resident now
#pragma unroll
            for (int ti = 0; ti < 4; ti++)
#pragma unroll
                for (int ks = 0; ks < 4; ks++) {
                    int r   = wi + ti * 16 + m;
                    int pos = (ks * 4 + q) ^ xr;
                    afr[ti][ks] = *(const bf16x8*)(&Bs[0][r * DD + pos * 8]);
                }
        }
        asm volatile("s_waitcnt lgkmcnt(0)" ::: "memory");
        __syncthreads();

        STAGE128(&abf[(size_t)(row0 + 128) * DD], 0);   // A rows 128..255 -> Bs[0]
        __syncthreads();
        if (wv >= 4) {
#pragma unroll
            for (int ti = 0; ti < 4; ti++)
#pragma unroll
                for (int ks = 0; ks < 4; ks++) {
                    int r   = (wi - 128) + ti * 16 + m;
                    int pos = (ks * 4 + q) ^ xr;
                    afr[ti][ks] = *(const bf16x8*)(&Bs[0][r * DD + pos * 8]);
                }
        }
        asm volatile("s_waitcnt lgkmcnt(0)" ::: "memory");
        __syncthreads();

        // issue B tile1 -> Bs[0] (4 outstanding entering the loop)
        STAGE128(&bbf[(size_t)(j0 + 128) * DD], 0);

        float rs[4][4];
#pragma unroll
        for (int ti = 0; ti < 4; ti++)
#pragma unroll
            for (int rg = 0; rg < 4; rg++) rs[ti][rg] = 0.f;

        const f32x4 zero = {0.f, 0.f, 0.f, 0.f};
        f32x4 acc[4][4];

#define COMPUTE_TILE(BUF)                                                              \
        {                                                                              \
            __builtin_amdgcn_s_setprio(1);                                             \
            _Pragma("unroll")                                                          \
            for (int ks = 0; ks < 4; ks++) {                                           \
                bf16x8 bfr[4];                                                         \
                _Pragma("unroll")                                                      \
                for (int tj = 0; tj < 4; tj++) {                                       \
                    int r   = wj + tj * 16 + m;                                        \
                    int pos = (ks * 4 + q) ^ xr;                                       \
                    bfr[tj] = *(const bf16x8*)(&Bs[BUF][r * DD + pos * 8]);            \
                }                                                                      \
                _Pragma("unroll")                                                      \
                for (int ti = 0; ti < 4; ti++)                                         \
                    _Pragma("unroll")                                                  \
                    for (int tj = 0; tj < 4; tj++)                                     \
                        acc[ti][tj] = __builtin_amdgcn_mfma_f32_16x16x32_bf16(         \
                            afr[ti][ks], bfr[tj], (ks == 0) ? zero : acc[ti][tj],      \
                            0, 0, 0);                                                  \
            }                                                                          \
            __builtin_amdgcn_s_setprio(0);                                             \
        }

#define EPILOGUE()                                                                     \
        _Pragma("unroll")                                                              \
        for (int ti = 0; ti < 4; ti++)                                                 \
            _Pragma("unroll")                                                          \
            for (int tj = 0; tj < 4; tj++) {                                           \
                f32x4 c = acc[ti][tj];                                                 \
                rs[ti][0] += EXP2F(c[0]);                                              \
                rs[ti][1] += EXP2F(c[1]);                                              \
                rs[ti][2] += EXP2F(c[2]);                                              \
                rs[ti][3] += EXP2F(c[3]);                                              \
            }

        // ---- steady state: tiles 0..5 (tile jt lives in Bs[(jt+1)&1]) ----
#pragma unroll 2
        for (int jt = 0; jt < 6; jt++) {
            const int cb = (jt + 1) & 1;
            COMPUTE_TILE(cb);
            asm volatile("s_waitcnt lgkmcnt(0)" ::: "memory"); // bfr reads done
            __builtin_amdgcn_s_barrier();                      // all waves done with Bs[cb]
            STAGE128(&bbf[(size_t)(j0 + (jt + 2) * 128) * DD], cb);  // issue jt+2
            EPILOGUE();                                        // register-only; covers flight
            // wait own tile jt+1 loads (4 newest = jt+2's stay IN FLIGHT across barrier)
            asm volatile("s_waitcnt vmcnt(4)" ::: "memory");
            __builtin_amdgcn_s_barrier();
        }
        {   // jt = 6: compute Bs[1]; nothing left to stage
            COMPUTE_TILE(1);
            EPILOGUE();
            asm volatile("s_waitcnt vmcnt(0)" ::: "memory");   // tile7 landed
            __builtin_amdgcn_s_barrier();
        }
        {   // jt = 7: last tile from Bs[0]
            COMPUTE_TILE(0);
            EPILOGUE();
        }

#undef COMPUTE_TILE
#undef STAGE128
#undef EPILOGUE

        // ---- reduce over the 16 col-lanes ----
#pragma unroll
        for (int ti = 0; ti < 4; ti++)
#pragma unroll
            for (int rg = 0; rg < 4; rg++) {
                float v = rs[ti][rg];
                v += __shfl_xor(v, 1);
                v += __shfl_xor(v, 2);
                v += __shfl_xor(v, 4);
                v += __shfl_xor(v, 8);
                rs[ti][rg] = v;
            }

        // ---- cross-wave combine (odd waves deposit; even waves add + store) ----
        if ((wv & 1) == 1 && m == 0) {
#pragma unroll
            for (int ti = 0; ti < 4; ti++)
#pragma unroll
                for (int rg = 0; rg < 4; rg++)
                    red[(wv >> 1) * 64 + ti * 16 + q * 4 + rg] = rs[ti][rg];
        }
        __syncthreads();
        if ((wv & 1) == 0 && m == 0) {
#pragma unroll
            for (int ti = 0; ti < 4; ti++)
#pragma unroll
                for (int rg = 0; rg < 4; rg++) {
                    int rloc = ti * 16 + q * 4 + rg;
                    st_agent(&Vp[(size_t)(bid & 7) * NN + row0 + wi + rloc],
                             rs[ti][rg] + red[(wv >> 1) * 64 + rloc]);
                }
        }
    }

    grid_sync(subcnt, root, gen, doneg, relay, myxcd, sub);

    // ================= phase C: per-class pairs — BLOCK-COOPERATIVE phase 1 =================
    {
        char* sm = (char*)SM;
        const int h  = tid >> 7;          // quarter 0..3 (owns class c = bid*4+h)
        const int ht = tid & 127;         // tid within quarter
        int*   memH    = (int*)  (sm + h * 18432);           // 256 B
        float* VadjH   = (float*)(sm + h * 18432 + 512);     // 256 B
        float* ScH     = (float*)(sm + h * 18432 + 1024);    // 16 KB
        float* psH     = (float*)(sm + h * 18432 + 17408);   // 8 B (2 waves/quarter)
        int*   csH     = (int*)  (sm + h * 18432 + 17424);   // 8 B
        int*   mcs     = (int*)(sm + 73728);                 // [4]
        int*   cum     = (int*)(sm + 73744);                 // [5]

        const int c = bid * 4 + h;        // classes 0..1023
        int mc = cnt[c];                  // first in-kernel read -> L2 miss -> fresh LLC
        if (mc > MAXCLS) mc = MAXCLS;
        if (ht == 0) mcs[h] = mc;

        float vsum = 0.f;
        if (ht < mc) {
            int r = list[c * MAXCLS + ht];
            memH[ht] = r;
#pragma unroll
            for (int jc = 0; jc < NCHUNK; jc++) vsum += Vp[(size_t)jc * NN + r];
        }
        __syncthreads();
        if (tid == 0) {
            int s = 0;
#pragma unroll
            for (int k = 0; k < 4; k++) { cum[k] = s; s += mcs[k] * mcs[k]; }
            cum[4] = s;
        }
        __syncthreads();

        // phase 1: ALL 32 16-lane groups process the 4 classes' combined pair space
        // (same per-dot lane pattern as prior rounds: 8 fmaf/lane + 4 shfl_xor)
        const int g = tid >> 4;           // 0..31
        const int l = tid & 15;
        const int tot = cum[4];
        for (int pp = g; pp < tot; pp += 32) {
            int k = (pp >= cum[2]) ? ((pp >= cum[3]) ? 3 : 2) : ((pp >= cum[1]) ? 1 : 0);
            int lp = pp - cum[k];
            int mck = mcs[k];
            int i = lp / mck;
            int j = lp - i * mck;
            int* memK = (int*)(sm + k * 18432);
            int ri = memK[i], rj = memK[j];
            const float4* ar = (const float4*)(a + (size_t)ri * DD) + l * 2;
            const float4* br = (const float4*)(b + (size_t)rj * DD) + l * 2;
            float4 a0 = ar[0], a1 = ar[1];
            float4 b0 = br[0], b1 = br[1];
            float s = 0.f;
            s = fmaf(a0.x, b0.x, s); s = fmaf(a0.y, b0.y, s);
            s = fmaf(a0.z, b0.z, s); s = fmaf(a0.w, b0.w, s);
            s = fmaf(a1.x, b1.x, s); s = fmaf(a1.y, b1.y, s);
            s = fmaf(a1.z, b1.z, s); s = fmaf(a1.w, b1.w, s);
            s += __shfl_xor(s, 1);
            s += __shfl_xor(s, 2);
            s += __shfl_xor(s, 4);
            s += __shfl_xor(s, 8);
            if (l == 0) ((float*)(sm + k * 18432 + 1024))[i * MAXCLS + j] = s;
        }
        __syncthreads();

        // deterministic per-row exp-sum (ascending j == previous pp-ordered atomics)
        if (ht < mc) {
            float se = 0.f;
            for (int j = 0; j < mc; j++) se += __expf(ScH[ht * MAXCLS + j]);
            VadjH[ht] = E1 * (vsum - se);
        }
        __syncthreads();

        // phase 2: one thread per ordered pair (i != j), 128 threads per quarter
        const int tot1 = mc * mc;
        float partial = 0.f;
        int   count   = 0;
        for (int pp = ht; pp < tot1; pp += 128) {
            int i = pp / mc;
            int j = pp - i * mc;
            if (i != j) {
                float hg = fmaxf(logf(VadjH[i] + VadjH[j]) - ScH[i * MAXCLS + j], 0.f);
                partial += hg * hg;
                count++;
            }
        }
        for (int off = 32; off > 0; off >>= 1) {
            partial += __shfl_down(partial, off);
            count   += __shfl_down(count, off);
        }
        if ((ht & 63) == 0) { psH[ht >> 6] = partial; csH[ht >> 6] = count; }
        __syncthreads();
        if (ht == 0) {
            st_agent(&classLoss[c], psH[0] + psH[1]);
            st_agent(&classCnt[c],  csH[0] + csH[1]);
        }
    }

    // ========== finalize: spread arrival tree; LAST block reduces, others exit ==========
    __syncthreads();   // all waves drain vmcnt -> this block's sc1 stores are at LLC
    __shared__ int amLast;
    if (tid == 0) {
        int last = 0;
        int v = __hip_atomic_fetch_add(&subcnt[sub * 32], 1,
                                       __ATOMIC_RELAXED, __HIP_MEMORY_SCOPE_AGENT);
        if (v == (NBLK / 8) - 1) {
            __hip_atomic_store(&subcnt[sub * 32], 0, __ATOMIC_RELAXED, __HIP_MEMORY_SCOPE_AGENT);
            int r = __hip_atomic_fetch_add(root, 1, __ATOMIC_RELAXED, __HIP_MEMORY_SCOPE_AGENT);
            if (r == 7) { __hip_atomic_store(root, 0, __ATOMIC_RELAXED, __HIP_MEMORY_SCOPE_AGENT); last = 1; }
        }
        amLast = last;
    }
    __syncthreads();
    if (amLast) {
        __shared__ double dred[8];
        __shared__ long long cred[8];
        const int lane = tid & 63, wvv = tid >> 6;
        double dls = 0.0;
        long long dct = 0;
        for (int k = tid; k < 1024; k += TPB) {
            dls += (double)__hip_atomic_load(&classLoss[k], __ATOMIC_RELAXED, __HIP_MEMORY_SCOPE_AGENT);
            dct += (long long)__hip_atomic_load(&classCnt[k], __ATOMIC_RELAXED, __HIP_MEMORY_SCOPE_AGENT);
        }
        for (int off = 32; off > 0; off >>= 1) {
            dls += __shfl_down(dls, off);
            dct += __shfl_down(dct, off);
        }
        if (lane == 0) { dred[wvv] = dls; cred[wvv] = dct; }
        __syncthreads();
        if (tid == 0) {
            double ls = 0.0;
            long long np = 0;
#pragma unroll
            for (int w = 0; w < 8; w++) { ls += dred[w]; np += cred[w]; }
            out[0] = (float)(ls / (2.0 * (double)np));
        }
    }
}

// ---------------- launch ----------------
extern "C" void kernel_launch(void* const* d_in, const int* in_sizes, int n_in,
                              void* d_out, int out_size, void* d_ws, size_t ws_size,
                              hipStream_t stream)
{
    const float* a      = (const float*)d_in[0];
    const float* b      = (const float*)d_in[1];
    const int*   labels = (const int*)d_in[2];
    float* out = (float*)d_out;

    char* ws = (char*)d_ws;
    // ws layout:
    //   [0, 2MB)   a_bf16 (scaled by log2e)    [2MB, 4MB)  b_bf16
    //   base2 = 4MB (first 8KB memset to 0); every barrier word on its OWN 128B line:
    //     +0     cnt[1024]              4096 B
    //     +4096  subcnt[8]  @128B stride  1 KB
    //     +5120  root
    //     +5248  gen
    //     +5376  claim[8]   @128B stride  1 KB
    //     +6400  doneg[8]   @128B stride  1 KB
    //     +8192  classLoss[1024] f32    4096 B
    //     +12288 classCnt[1024] int     4096 B
    //     +16384 list[1024*64]          256 KB
    //     +278528 Vp[8*8192] f32        256 KB
    unsigned short* abf = (unsigned short*)ws;
    unsigned short* bbf = (unsigned short*)(ws + 2097152);
    char*     base2     = ws + 4194304;
    int*      cnt       = (int*)(base2);
    int*      subcnt    = (int*)(base2 + 4096);
    int*      root      = (int*)(base2 + 5120);
    unsigned int* gen   = (unsigned int*)(base2 + 5248);
    int*      claim     = (int*)(base2 + 5376);
    unsigned int* doneg = (unsigned int*)(base2 + 6400);
    float*    classLoss = (float*)(base2 + 8192);
    int*      classCnt  = (int*)(base2 + 12288);
    int*      list      = (int*)(base2 + 16384);
    float*    Vp        = (float*)(base2 + 278528);

    (void)hipMemsetAsync(cnt, 0, 8192, stream);   // zeros cnt + all barrier state

    ml_fused_kernel<<<NBLK, TPB, 0, stream>>>(
        a, b, labels, abf, bbf, cnt, list, Vp, classLoss, classCnt, out,
        subcnt, root, gen, claim, doneg);
}